// Round 7
// baseline (84.155 us; speedup 1.0000x reference)
//
#include <hip/hip_runtime.h>
#include <hip/hip_bf16.h>

#define TDIM 1024
#define KDIM 32
#define BDIM 512
#define NWAVES 2048   // 512 blocks x 4 waves, all co-resident (persistent)

typedef short bf16x8 __attribute__((ext_vector_type(8)));
typedef float f32x4  __attribute__((ext_vector_type(4)));

__device__ __forceinline__ unsigned short f2bf(float x) {
    __hip_bfloat16 h = __float2bfloat16(x);
    return *reinterpret_cast<unsigned short*>(&h);
}

__device__ __forceinline__ int read_len(const int* __restrict__ lengths32, int b) {
    // int64 little-endian: int32 view at odd index 1 is high word of lengths[0] == 0.
    // int32: lengths[1] in [1,1024], never 0.  (verified rounds 1-6)
    const bool is64 = (lengths32[1] == 0);
    int len = is64 ? lengths32[2 * b] : lengths32[b];
    return len < 1 ? 1 : (len > TDIM ? TDIM : len);
}

// ---------------- K1: PERSISTENT per-(batch, chunk) product kernel --------
// 2048 waves stay resident; each loops over slots j = gw + k*NWAVES of the
// (b = j/NCH, c = j%NCH) chunk grid, skipping dead chunks via LDS-cached
// lengths. Emission staging: per-wave double-buffered LDS slices, next job's
// global_load_lds DMA issued before computing current job, counted vmcnt(8).
// Inner math identical to round 6 (collapsed chain: A = Ef*d, B = bf16(C)).
template<int CHS, int NCH>
__global__ __launch_bounds__(256) void crf_chunk_persist(
    const float* __restrict__ emissions,    // [B, T, K]
    const int*   __restrict__ lengths32,
    const float* __restrict__ transitions,  // [K, K]
    unsigned int* __restrict__ Pout,        // [B][NCH][1024] bf16 as 512 dwords
    int*          __restrict__ toteOut)     // [B][NCH]
{
    constexpr bool DBUF = (CHS == 64);
    constexpr int  NSEG = CHS * KDIM / 256;        // 1KB DMA segments per job
    __shared__ float lds_all[DBUF ? 8 : 4][CHS * KDIM];
    __shared__ int   ld_len[BDIM];

    const int wid  = threadIdx.x >> 6;
    const int lane = threadIdx.x & 63;
    const int n    = lane & 15;
    const int g    = (lane >> 4) & 3;
    const int gw   = blockIdx.x * 4 + wid;

    for (int i = threadIdx.x; i < BDIM; i += 256)
        ld_len[i] = read_len(lengths32, i);

    // static E^T factors (once per wave): elem e <-> contraction k = rho(g,e)
    f32x4 Ef00, Ef01, Ef10, Ef11;
#pragma unroll
    for (int e = 0; e < 4; ++e) {
        Ef00[e] = __expf(transitions[(4 * g + e) * KDIM + n]);
        Ef01[e] = __expf(transitions[(16 + 4 * g + e) * KDIM + n]);
        Ef10[e] = __expf(transitions[(4 * g + e) * KDIM + 16 + n]);
        Ef11[e] = __expf(transitions[(16 + 4 * g + e) * KDIM + 16 + n]);
    }
    __syncthreads();

    float* slA = lds_all[DBUF ? wid * 2 : wid];
    float* slB = DBUF ? lds_all[wid * 2 + 1] : slA;

    auto alivecnt = [&](int j) -> int {
        int b = j / NCH, c = j % NCH;
        int cnt = ld_len[b] - (1 + c * CHS);
        return cnt > CHS ? CHS : cnt;
    };
    auto nextjob = [&](int jstart) -> int {
        for (int j = jstart; j < BDIM * NCH; j += NWAVES)
            if (alivecnt(j) > 0) return j;
        return -1;
    };
    auto ISSUE = [&](int j, float* sl) {
        int b = j / NCH, c = j % NCH;
        int t0 = 1 + c * CHS;
        int base_t = (t0 + CHS > TDIM) ? (TDIM - CHS) : t0;
        const float* src = emissions + ((size_t)b * TDIM + base_t) * KDIM;
#pragma unroll
        for (int s = 0; s < NSEG; ++s)
            __builtin_amdgcn_global_load_lds(
                (const __attribute__((address_space(1))) void*)(src + s * 256 + lane * 4),
                (__attribute__((address_space(3))) void*)(sl + s * 256), 16, 0, 0);
    };

    auto COMPUTE = [&](int j, float* myl) {
        const int b = j / NCH, c = j % NCH;
        const int count = alivecnt(j);
        const int t0 = 1 + c * CHS;
        const int shift = (t0 + CHS > TDIM) ? (t0 - (TDIM - CHS)) : 0;

        // exp pre-pass in place (per-wave slice; DMA already waited)
        f32x4* mylv = (f32x4*)myl;
#pragma unroll
        for (int r = 0; r < NSEG; ++r) {
            f32x4 v = mylv[r * 64 + lane];
#pragma unroll
            for (int e = 0; e < 4; ++e) v[e] = __expf(v[e]);
            mylv[r * 64 + lane] = v;
        }
        asm volatile("s_waitcnt lgkmcnt(0)" ::: "memory");
        __builtin_amdgcn_sched_barrier(0);

        f32x4 C00, C01, C10, C11;
#pragma unroll
        for (int q = 0; q < 4; ++q) {
            float d = (4 * g + q == n) ? 1.0f : 0.0f;
            C00[q] = d; C11[q] = d; C01[q] = 0.0f; C10[q] = 0.0f;
        }
        float sf = 1.0f; int pend = 0, tote = 0;
        const f32x4 zero = {0.0f, 0.0f, 0.0f, 0.0f};

        auto STEP = [&](f32x4 e0, f32x4 e1) {
            f32x4 a00 = Ef00 * e0, a01 = Ef01 * e1, a10 = Ef10 * e0, a11 = Ef11 * e1;
            bf16x8 A0, A1, B0, B1;
#pragma unroll
            for (int q = 0; q < 4; ++q) {
                A0[q]     = (short)f2bf(a00[q]);
                A0[q + 4] = (short)f2bf(a01[q]);
                A1[q]     = (short)f2bf(a10[q]);
                A1[q + 4] = (short)f2bf(a11[q]);
                B0[q]     = (short)f2bf(C00[q]);
                B0[q + 4] = (short)f2bf(C10[q]);
                B1[q]     = (short)f2bf(C01[q]);
                B1[q + 4] = (short)f2bf(C11[q]);
            }
            C00 = __builtin_amdgcn_mfma_f32_16x16x32_bf16(A0, B0, zero, 0, 0, 0);
            C01 = __builtin_amdgcn_mfma_f32_16x16x32_bf16(A0, B1, zero, 0, 0, 0);
            C10 = __builtin_amdgcn_mfma_f32_16x16x32_bf16(A1, B0, zero, 0, 0, 0);
            C11 = __builtin_amdgcn_mfma_f32_16x16x32_bf16(A1, B1, zero, 0, 0, 0);
        };
        auto RESCALE = [&]() {
            int bits = __builtin_amdgcn_readfirstlane(__float_as_int(C00[0]));
            pend = ((bits >> 23) & 255) - 127;
            sf = __uint_as_float((unsigned)(127 - pend) << 23);
        };

        if (count == CHS) {
            f32x4 pipe[2][2];
            pipe[0][0] = mylv[0 * 8 + g]; pipe[0][1] = mylv[0 * 8 + 4 + g];
            pipe[1][0] = mylv[1 * 8 + g]; pipe[1][1] = mylv[1 * 8 + 4 + g];
            constexpr int NQ = CHS / 4;
            for (int tq = 0; tq < NQ; ++tq) {
#pragma unroll
                for (int u = 0; u < 4; ++u) {
                    const int s = u & 1;
                    f32x4 e0 = pipe[s][0], e1 = pipe[s][1];
                    int tl = 4 * tq + u + 2; if (tl > CHS - 1) tl = CHS - 1;
                    pipe[s][0] = mylv[tl * 8 + g];
                    pipe[s][1] = mylv[tl * 8 + 4 + g];
                    if (u == 0) {
#pragma unroll
                        for (int e = 0; e < 4; ++e) { e0[e] *= sf; e1[e] *= sf; }
                        tote += pend;
                    }
                    STEP(e0, e1);
                    if (u == 3) RESCALE();
                }
            }
        } else {
            for (int tau = 0; tau < count; ++tau) {
                f32x4 e0 = mylv[(tau + shift) * 8 + g];
                f32x4 e1 = mylv[(tau + shift) * 8 + 4 + g];
#pragma unroll
                for (int e = 0; e < 4; ++e) { e0[e] *= sf; e1[e] *= sf; }
                tote += pend;
                STEP(e0, e1);
                RESCALE();
            }
        }

        unsigned int* outP = Pout + ((size_t)b * NCH + c) * 512;
#pragma unroll
        for (int p = 0; p < 2; ++p) {
            int q = 2 * p;
            outP[n * 16        + (4 * g + q) / 2]      = (unsigned)f2bf(C00[q]) | ((unsigned)f2bf(C00[q + 1]) << 16);
            outP[(16 + n) * 16 + (4 * g + q) / 2]      = (unsigned)f2bf(C01[q]) | ((unsigned)f2bf(C01[q + 1]) << 16);
            outP[n * 16        + (16 + 4 * g + q) / 2] = (unsigned)f2bf(C10[q]) | ((unsigned)f2bf(C10[q + 1]) << 16);
            outP[(16 + n) * 16 + (16 + 4 * g + q) / 2] = (unsigned)f2bf(C11[q]) | ((unsigned)f2bf(C11[q + 1]) << 16);
        }
        if (lane == 0) toteOut[b * NCH + c] = tote;
    };

    int jcur = nextjob(gw);
    if constexpr (DBUF) {
        if (jcur >= 0) ISSUE(jcur, slA);
        bool useA = true;
        while (jcur >= 0) {
            int jnext = nextjob(jcur + NWAVES);
            if (jnext >= 0) {
                ISSUE(jnext, useA ? slB : slA);
                asm volatile("s_waitcnt vmcnt(8)" ::: "memory");   // = NSEG newer loads in flight
            } else {
                asm volatile("s_waitcnt vmcnt(0)" ::: "memory");
            }
            __builtin_amdgcn_sched_barrier(0);
            COMPUTE(jcur, useA ? slA : slB);
            jcur = jnext; useA = !useA;
        }
    } else {
        while (jcur >= 0) {
            ISSUE(jcur, slA);
            asm volatile("s_waitcnt vmcnt(0)" ::: "memory");
            __builtin_amdgcn_sched_barrier(0);
            COMPUTE(jcur, slA);
            jcur = nextjob(jcur + NWAVES);
        }
    }
}

// ---------------- K2: chain chunk matrices through alpha ------------------
template<int NCH, int CHS>
__global__ __launch_bounds__(64) void crf_combine_kernel(
    const float* __restrict__ emissions,
    const int*   __restrict__ lengths32,
    const float* __restrict__ head_t,
    const float* __restrict__ last_t,
    const unsigned short* __restrict__ Pbuf,  // [B][NCH][1024] bf16 col-major
    const int*   __restrict__ toteBuf,
    float*       __restrict__ out)
{
    const int b    = blockIdx.x;
    const int lane = threadIdx.x;
    const int j    = lane & 31;

    const int len = read_len(lengths32, b);
    int nAlive = (len - 1 + CHS - 1) / CHS;
    if (nAlive > NCH) nAlive = NCH;

    float alpha = __expf(head_t[j] + emissions[(size_t)b * TDIM * KDIM + j]);
    int tote = 0;

    const char* base = (const char*)(Pbuf + (size_t)b * NCH * 1024);

    auto LOADC = [&](int cix, uint4 dst[4]) {
        int cc = cix < NCH ? cix : NCH - 1;
        const uint4* pc = (const uint4*)(base + (size_t)cc * 2048 + (size_t)j * 64);
#pragma unroll
        for (int w = 0; w < 4; ++w) dst[w] = pc[w];
    };

    uint4 cur[4], nx1[4];
    LOADC(0, cur);
    LOADC(1, nx1);

    for (int cix = 0; cix < nAlive; ++cix) {
        uint4 nx2[4];
        LOADC(cix + 2, nx2);

        float a0 = 0.0f, a1 = 0.0f;
#pragma unroll
        for (int w = 0; w < 4; ++w) {
            unsigned d[4] = {cur[w].x, cur[w].y, cur[w].z, cur[w].w};
#pragma unroll
            for (int h = 0; h < 4; ++h) {
                int r = w * 8 + h * 2;
                float plo = __uint_as_float(d[h] << 16);           // row r,   col j
                float phi = __uint_as_float(d[h] & 0xffff0000u);   // row r+1, col j
                float al  = __int_as_float(__builtin_amdgcn_readlane(__float_as_int(alpha), r));
                float ah  = __int_as_float(__builtin_amdgcn_readlane(__float_as_int(alpha), r + 1));
                a0 = fmaf(plo, al, a0);
                a1 = fmaf(phi, ah, a1);
            }
        }
        float acc = a0 + a1;
        int bits = __builtin_amdgcn_readfirstlane(__float_as_int(acc));
        int s = ((bits >> 23) & 255) - 127;
        alpha = acc * __uint_as_float((unsigned)(127 - s) << 23);
        tote += s + toteBuf[b * NCH + cix];
#pragma unroll
        for (int w = 0; w < 4; ++w) { cur[w] = nx1[w]; nx1[w] = nx2[w]; }
    }

    float pp = alpha * __expf(last_t[j]);
#pragma unroll
    for (int mm = 16; mm >= 1; mm >>= 1)
        pp += __shfl_xor(pp, mm, 64);

    if (lane == 0)
        out[b] = __logf(pp) + (float)tote * 0.69314718055994531f;
}

extern "C" void kernel_launch(void* const* d_in, const int* in_sizes, int n_in,
                              void* d_out, int out_size, void* d_ws, size_t ws_size,
                              hipStream_t stream)
{
    const float* emissions   = (const float*)d_in[0];
    const int*   lengths     = (const int*)d_in[1];
    const float* transitions = (const float*)d_in[2];
    const float* head_t      = (const float*)d_in[3];
    const float* last_t      = (const float*)d_in[4];
    float* out = (float*)d_out;
    const int B = out_size;  // 512

    unsigned int* Pbuf = (unsigned int*)d_ws;

    const size_t need16 = (size_t)B * 16 * 2048 + (size_t)B * 16 * 4;
    if (ws_size >= need16) {
        int* toteBf = (int*)((char*)d_ws + (size_t)B * 16 * 2048);
        crf_chunk_persist<64, 16><<<512, 256, 0, stream>>>(emissions, lengths, transitions, Pbuf, toteBf);
        crf_combine_kernel<16, 64><<<B, 64, 0, stream>>>(emissions, lengths, head_t, last_t,
                                                         (const unsigned short*)Pbuf, toteBf, out);
    } else {
        int* toteBf = (int*)((char*)d_ws + (size_t)B * 8 * 2048);
        crf_chunk_persist<128, 8><<<512, 256, 0, stream>>>(emissions, lengths, transitions, Pbuf, toteBf);
        crf_combine_kernel<8, 128><<<B, 64, 0, stream>>>(emissions, lengths, head_t, last_t,
                                                         (const unsigned short*)Pbuf, toteBf, out);
    }
}

// Round 9
// 67.742 us; speedup vs baseline: 1.2423x; 1.2423x over previous
//
#include <hip/hip_runtime.h>
#include <hip/hip_bf16.h>

#define TDIM 1024
#define KDIM 32

typedef short bf16x8 __attribute__((ext_vector_type(8)));
typedef float f32x4  __attribute__((ext_vector_type(4)));

__device__ __forceinline__ unsigned short f2bf(float x) {
    __hip_bfloat16 h = __float2bfloat16(x);
    return *reinterpret_cast<unsigned short*>(&h);
}

__device__ __forceinline__ int read_len(const int* __restrict__ lengths32, int b) {
    // int64 little-endian: int32 view at odd index 1 is high word of lengths[0] == 0.
    // int32: lengths[1] in [1,1024], never 0.  (verified rounds 1-7)
    const bool is64 = (lengths32[1] == 0);
    int len = is64 ? lengths32[2 * b] : lengths32[b];
    return len < 1 ? 1 : (len > TDIM ? TDIM : len);
}

// ---------------- K1: per-(batch, chunk) 32x32 product matrix -------------
// Round 6 structure; MFMA via ONE inline-asm block with explicit hazard
// s_nops (s_nop 3 before: VALU-write->MFMA-read; 2x s_nop 7 after:
// MFMA-D-write->VALU-read). Accumulator chain lives in arch VGPRs; no
// compiler-inserted AGPR moves / hazard stalls on the critical path.
template<int CHS, int NCH>
__global__ __launch_bounds__(256, 4) void crf_chunk_kernel(
    const float* __restrict__ emissions,    // [B, T, K]
    const int*   __restrict__ lengths32,
    const float* __restrict__ transitions,  // [K, K]
    unsigned int* __restrict__ Pout,        // [B][NCH][1024] bf16 as 512 dwords
    int*          __restrict__ toteOut)     // [B][NCH]
{
    __shared__ float lds_all[4][CHS * KDIM];
    const int wid  = threadIdx.x >> 6;
    const int lane = threadIdx.x & 63;
    const int n    = lane & 15;
    const int g    = (lane >> 4) & 3;
    const int c    = blockIdx.x * 4 + wid;
    const int b    = blockIdx.y;

    const int len = read_len(lengths32, b);
    const int t0  = 1 + c * CHS;
    int count = len - t0; count = count > CHS ? CHS : count;
    if (count <= 0) return;                  // dead chunk

    // ---- stage CHS emission rows into this wave's LDS slice (async DMA) ----
    int base_t = t0, shift = 0;
    if (t0 + CHS > TDIM) { base_t = TDIM - CHS; shift = t0 - base_t; }
    const float* src = emissions + ((size_t)b * TDIM + base_t) * KDIM;
    float* myl = lds_all[wid];
    constexpr int NSEG = CHS * KDIM / 256;   // 1KB segments
#pragma unroll
    for (int s = 0; s < NSEG; ++s)
        __builtin_amdgcn_global_load_lds(
            (const __attribute__((address_space(1))) void*)(src + s * 256 + lane * 4),
            (__attribute__((address_space(3))) void*)(myl + s * 256), 16, 0, 0);

    // static E^T factors in f32 (A-operand element e <-> contraction k = rho(g,e))
    f32x4 Ef00, Ef01, Ef10, Ef11;
#pragma unroll
    for (int e = 0; e < 4; ++e) {
        Ef00[e] = __expf(transitions[(4 * g + e) * KDIM + n]);
        Ef01[e] = __expf(transitions[(16 + 4 * g + e) * KDIM + n]);
        Ef10[e] = __expf(transitions[(4 * g + e) * KDIM + 16 + n]);
        Ef11[e] = __expf(transitions[(16 + 4 * g + e) * KDIM + 16 + n]);
    }

    asm volatile("s_waitcnt vmcnt(0)" ::: "memory");
    __builtin_amdgcn_sched_barrier(0);

    // ---- exp pre-pass in place (per-wave slice) ----
    f32x4* mylv = (f32x4*)myl;
#pragma unroll
    for (int r = 0; r < NSEG; ++r) {
        f32x4 v = mylv[r * 64 + lane];
#pragma unroll
        for (int e = 0; e < 4; ++e) v[e] = __expf(v[e]);
        mylv[r * 64 + lane] = v;
    }
    asm volatile("s_waitcnt lgkmcnt(0)" ::: "memory");
    __builtin_amdgcn_sched_barrier(0);

    // ---- running product in VGPR C-frags ----
    f32x4 C00, C01, C10, C11;
#pragma unroll
    for (int q = 0; q < 4; ++q) {
        float d = (4 * g + q == n) ? 1.0f : 0.0f;
        C00[q] = d; C11[q] = d; C01[q] = 0.0f; C10[q] = 0.0f;
    }
    float sf = 1.0f; int pend = 0, tote = 0;
    f32x4 zero = {0.0f, 0.0f, 0.0f, 0.0f};
    asm volatile("" : "+v"(zero));   // pin zero C-operand in VGPRs

    auto STEP = [&](f32x4 e0, f32x4 e1) {
        // A_t = E^T scaled per-column by d (emission-only -> off critical path)
        f32x4 a00 = Ef00 * e0, a01 = Ef01 * e1, a10 = Ef10 * e0, a11 = Ef11 * e1;
        bf16x8 A0, A1, B0, B1;
#pragma unroll
        for (int q = 0; q < 4; ++q) {
            A0[q]     = (short)f2bf(a00[q]);
            A0[q + 4] = (short)f2bf(a01[q]);
            A1[q]     = (short)f2bf(a10[q]);
            A1[q + 4] = (short)f2bf(a11[q]);
            B0[q]     = (short)f2bf(C00[q]);   // B = bf16(previous C): the only
            B0[q + 4] = (short)f2bf(C10[q]);   // ops on the MFMA->MFMA chain
            B1[q]     = (short)f2bf(C01[q]);
            B1[q + 4] = (short)f2bf(C11[q]);
        }
        f32x4 n00, n01, n10, n11;
        // One block: s_nop 3 covers VALU(cvt)->MFMA src-read hazard;
        // 2x s_nop 7 (16 wait states) covers MFMA D-write -> VALU read.
        asm("s_nop 3\n\t"
            "v_mfma_f32_16x16x32_bf16 %0, %4, %6, %8\n\t"
            "v_mfma_f32_16x16x32_bf16 %1, %4, %7, %8\n\t"
            "v_mfma_f32_16x16x32_bf16 %2, %5, %6, %8\n\t"
            "v_mfma_f32_16x16x32_bf16 %3, %5, %7, %8\n\t"
            "s_nop 7\n\t"
            "s_nop 7"
            : "=&v"(n00), "=&v"(n01), "=&v"(n10), "=&v"(n11)
            : "v"(A0), "v"(A1), "v"(B0), "v"(B1), "v"(zero));
        C00 = n00; C01 = n01; C10 = n10; C11 = n11;
    };
    auto RESCALE = [&]() {
        int bits = __builtin_amdgcn_readfirstlane(__float_as_int(C00[0]));
        pend = ((bits >> 23) & 255) - 127;
        sf = __uint_as_float((unsigned)(127 - pend) << 23);
    };

    if (count == CHS) {
        // depth-2 LDS read pipeline, static slot = u&1
        f32x4 pipe[2][2];
        pipe[0][0] = mylv[0 * 8 + g]; pipe[0][1] = mylv[0 * 8 + 4 + g];
        pipe[1][0] = mylv[1 * 8 + g]; pipe[1][1] = mylv[1 * 8 + 4 + g];
        constexpr int NQ = CHS / 4;
        for (int tq = 0; tq < NQ; ++tq) {
#pragma unroll
            for (int u = 0; u < 4; ++u) {
                const int s = u & 1;
                f32x4 e0 = pipe[s][0], e1 = pipe[s][1];
                int tl = 4 * tq + u + 2; if (tl > CHS - 1) tl = CHS - 1;
                pipe[s][0] = mylv[tl * 8 + g];
                pipe[s][1] = mylv[tl * 8 + 4 + g];
                if (u == 0) {
#pragma unroll
                    for (int e = 0; e < 4; ++e) { e0[e] *= sf; e1[e] *= sf; }
                    tote += pend;
                }
                STEP(e0, e1);
                if (u == 3) RESCALE();
            }
        }
    } else {
        // boundary chunk: per-step fold + rescale
        for (int tau = 0; tau < count; ++tau) {
            f32x4 e0 = mylv[(tau + shift) * 8 + g];
            f32x4 e1 = mylv[(tau + shift) * 8 + 4 + g];
#pragma unroll
            for (int e = 0; e < 4; ++e) { e0[e] *= sf; e1[e] *= sf; }
            tote += pend;
            STEP(e0, e1);
            RESCALE();
        }
    }

    // store bf16 col-major: dword idx = col*16 + row/2
    unsigned int* outP = Pout + ((size_t)b * NCH + c) * 512;
#pragma unroll
    for (int p = 0; p < 2; ++p) {
        int q = 2 * p;
        outP[n * 16        + (4 * g + q) / 2]      = (unsigned)f2bf(C00[q]) | ((unsigned)f2bf(C00[q + 1]) << 16);
        outP[(16 + n) * 16 + (4 * g + q) / 2]      = (unsigned)f2bf(C01[q]) | ((unsigned)f2bf(C01[q + 1]) << 16);
        outP[n * 16        + (16 + 4 * g + q) / 2] = (unsigned)f2bf(C10[q]) | ((unsigned)f2bf(C10[q + 1]) << 16);
        outP[(16 + n) * 16 + (16 + 4 * g + q) / 2] = (unsigned)f2bf(C11[q]) | ((unsigned)f2bf(C11[q + 1]) << 16);
    }
    if (lane == 0) toteOut[b * NCH + c] = tote;
}

// ---------------- K2: chain chunk matrices through alpha ------------------
template<int NCH, int CHS>
__global__ __launch_bounds__(64) void crf_combine_kernel(
    const float* __restrict__ emissions,
    const int*   __restrict__ lengths32,
    const float* __restrict__ head_t,
    const float* __restrict__ last_t,
    const unsigned short* __restrict__ Pbuf,  // [B][NCH][1024] bf16 col-major
    const int*   __restrict__ toteBuf,
    float*       __restrict__ out)
{
    const int b    = blockIdx.x;
    const int lane = threadIdx.x;
    const int j    = lane & 31;

    const int len = read_len(lengths32, b);
    int nAlive = (len - 1 + CHS - 1) / CHS;
    if (nAlive > NCH) nAlive = NCH;

    float alpha = __expf(head_t[j] + emissions[(size_t)b * TDIM * KDIM + j]);
    int tote = 0;

    const char* base = (const char*)(Pbuf + (size_t)b * NCH * 1024);

    auto LOADC = [&](int cix, uint4 dst[4]) {
        int cc = cix < NCH ? cix : NCH - 1;
        const uint4* pc = (const uint4*)(base + (size_t)cc * 2048 + (size_t)j * 64);
#pragma unroll
        for (int w = 0; w < 4; ++w) dst[w] = pc[w];
    };

    uint4 cur[4], nx1[4];
    LOADC(0, cur);
    LOADC(1, nx1);

    for (int cix = 0; cix < nAlive; ++cix) {
        uint4 nx2[4];
        LOADC(cix + 2, nx2);

        float a0 = 0.0f, a1 = 0.0f;
#pragma unroll
        for (int w = 0; w < 4; ++w) {
            unsigned d[4] = {cur[w].x, cur[w].y, cur[w].z, cur[w].w};
#pragma unroll
            for (int h = 0; h < 4; ++h) {
                int r = w * 8 + h * 2;
                float plo = __uint_as_float(d[h] << 16);           // row r,   col j
                float phi = __uint_as_float(d[h] & 0xffff0000u);   // row r+1, col j
                float al  = __int_as_float(__builtin_amdgcn_readlane(__float_as_int(alpha), r));
                float ah  = __int_as_float(__builtin_amdgcn_readlane(__float_as_int(alpha), r + 1));
                a0 = fmaf(plo, al, a0);
                a1 = fmaf(phi, ah, a1);
            }
        }
        float acc = a0 + a1;
        int bits = __builtin_amdgcn_readfirstlane(__float_as_int(acc));
        int s = ((bits >> 23) & 255) - 127;
        alpha = acc * __uint_as_float((unsigned)(127 - s) << 23);
        tote += s + toteBuf[b * NCH + cix];
#pragma unroll
        for (int w = 0; w < 4; ++w) { cur[w] = nx1[w]; nx1[w] = nx2[w]; }
    }

    float pp = alpha * __expf(last_t[j]);
#pragma unroll
    for (int mm = 16; mm >= 1; mm >>= 1)
        pp += __shfl_xor(pp, mm, 64);

    if (lane == 0)
        out[b] = __logf(pp) + (float)tote * 0.69314718055994531f;
}

extern "C" void kernel_launch(void* const* d_in, const int* in_sizes, int n_in,
                              void* d_out, int out_size, void* d_ws, size_t ws_size,
                              hipStream_t stream)
{
    const float* emissions   = (const float*)d_in[0];
    const int*   lengths     = (const int*)d_in[1];
    const float* transitions = (const float*)d_in[2];
    const float* head_t      = (const float*)d_in[3];
    const float* last_t      = (const float*)d_in[4];
    float* out = (float*)d_out;
    const int B = out_size;  // 512

    unsigned int* Pbuf = (unsigned int*)d_ws;

    const size_t need16 = (size_t)B * 16 * 2048 + (size_t)B * 16 * 4;
    if (ws_size >= need16) {
        int* toteBf = (int*)((char*)d_ws + (size_t)B * 16 * 2048);
        dim3 g1(4, B);    // 4 blocks x 4 waves = 16 chunks of 64 steps
        crf_chunk_kernel<64, 16><<<g1, 256, 0, stream>>>(emissions, lengths, transitions, Pbuf, toteBf);
        crf_combine_kernel<16, 64><<<B, 64, 0, stream>>>(emissions, lengths, head_t, last_t,
                                                         (const unsigned short*)Pbuf, toteBf, out);
    } else {
        int* toteBf = (int*)((char*)d_ws + (size_t)B * 8 * 2048);
        dim3 g1(2, B);    // 2 blocks x 4 waves = 8 chunks of 128 steps
        crf_chunk_kernel<128, 8><<<g1, 256, 0, stream>>>(emissions, lengths, transitions, Pbuf, toteBf);
        crf_combine_kernel<8, 128><<<B, 64, 0, stream>>>(emissions, lengths, head_t, last_t,
                                                         (const unsigned short*)Pbuf, toteBf, out);
    }
}